// Round 2
// baseline (349.898 us; speedup 1.0000x reference)
//
#include <hip/hip_runtime.h>
#include <hip/hip_bf16.h>
#include <math.h>

// Problem constants
#define B_  4
#define S_  2048
#define D_  1024
#define H_  16
#define HD_ 64

typedef __bf16 bf16;
typedef __bf16 bf16x4 __attribute__((ext_vector_type(4)));
typedef __bf16 bf16x8 __attribute__((ext_vector_type(8)));
typedef float  floatx4 __attribute__((ext_vector_type(4)));
typedef unsigned short ushort8 __attribute__((ext_vector_type(8)));

// log2(e)/8: folds the 1/sqrt(64) attention scale AND the exp->exp2 change
// of base into the Q projection epilogue.
#define QSCALE 0.18033688011112042f

// Async global->LDS DMA, 16B/lane. LDS dest = wave-uniform base + lane*16.
__device__ __forceinline__ void async_load16(const bf16* g, bf16* l) {
  __builtin_amdgcn_global_load_lds(
      (const __attribute__((address_space(1))) void*)g,
      (__attribute__((address_space(3))) void*)l, 16, 0, 0);
}

// pack two f32 -> one dword of 2 bf16 (lo = a, hi = b)
__device__ __forceinline__ unsigned packbf2(float a, float b) {
  union { bf16 h[2]; unsigned u; } x;
  x.h[0] = (bf16)a; x.h[1] = (bf16)b;
  return x.u;
}

// ---------------------------------------------------------------------------
// fp32 -> bf16 cast for BOTH X inputs in one launch (8192 blocks each)
// ---------------------------------------------------------------------------
__global__ __launch_bounds__(256) void cast_both(
    const float* __restrict__ ina, bf16* __restrict__ outa,
    const float* __restrict__ inb, bf16* __restrict__ outb) {
  int bid = blockIdx.x;
  const float* in;
  bf16* out;
  int i;
  if (bid < 8192) { in = ina; out = outa; i = (bid * 256 + threadIdx.x) * 4; }
  else            { in = inb; out = outb; i = ((bid - 8192) * 256 + threadIdx.x) * 4; }
  float4 v = *reinterpret_cast<const float4*>(in + i);
  bf16x4 o;
  o[0] = (bf16)v.x; o[1] = (bf16)v.y; o[2] = (bf16)v.z; o[3] = (bf16)v.w;
  *reinterpret_cast<bf16x4*>(out + i) = o;
}

// ---------------------------------------------------------------------------
// fp32 [K][N] -> bf16 [N][K] transpose+cast for all 3 weights in one launch.
// K=1024 for all; N=1024 (q_w), 2048 (kv_w), 1024 (out_w).
// ---------------------------------------------------------------------------
__global__ __launch_bounds__(256) void transcast_all(
    const float* __restrict__ qw, bf16* __restrict__ qwT,
    const float* __restrict__ kvw, bf16* __restrict__ kvwT,
    const float* __restrict__ ow, bf16* __restrict__ owT) {
  __shared__ float tile[32][33];
  int bid = blockIdx.x;
  const float* in; bf16* out; int N, lb;
  if (bid < 1024)      { in = qw;  out = qwT;  N = 1024; lb = bid; }
  else if (bid < 3072) { in = kvw; out = kvwT; N = 2048; lb = bid - 1024; }
  else                 { in = ow;  out = owT;  N = 1024; lb = bid - 3072; }
  int nx = N >> 5;
  int n0 = (lb % nx) * 32, k0 = (lb / nx) * 32;
  int tx = threadIdx.x & 31, ty = threadIdx.x >> 5;  // 32 x 8
  #pragma unroll
  for (int i = ty; i < 32; i += 8)
    tile[i][tx] = in[(size_t)(k0 + i) * N + n0 + tx];
  __syncthreads();
  #pragma unroll
  for (int i = ty; i < 32; i += 8)
    out[(size_t)(n0 + i) * 1024 + k0 + tx] = (bf16)tile[tx][i];
}

// ---------------------------------------------------------------------------
// bf16 GEMM, m97 structure: C[M,N] = A[M,K] @ Bt[N,K]^T + bias[N]
// 128x128 tile, BK=64, global_load_lds(16B) staging, XOR-swizzled LDS.
// MODE 0: fp32 out row-major [M,N]
// MODE 1: bf16 out in Q layout [B,H,S,HD], scaled by QSCALE (N==1024)
// MODE 2: bf16 out; K half -> [B,H,S,HD]; V half -> TRANSPOSED [B,H,HD,S]
// ---------------------------------------------------------------------------
template <int MODE>
__global__ __launch_bounds__(256) void gemm_bt(
    const bf16* __restrict__ A, const bf16* __restrict__ Bt,
    const float* __restrict__ bias, void* __restrict__ out,
    int M, int N, int K) {
  __shared__ bf16 As[128][64];
  __shared__ bf16 Bs[128][64];

  const int tid  = threadIdx.x;
  const int m0   = blockIdx.y * 128;
  const int n0   = blockIdx.x * 128;
  const int w    = tid >> 6;
  const int lane = tid & 63;
  const int lr   = lane & 15;
  const int lq   = lane >> 4;
  const int wm   = (w >> 1) * 64;
  const int wn   = (w & 1) * 64;

  const int srow = lane >> 3;
  const int sg   = (lane & 7) ^ srow;
  const bf16* aptr = A  + (size_t)(m0 + 32 * w + srow) * K + 8 * sg;
  const bf16* bptr = Bt + (size_t)(n0 + 32 * w + srow) * K + 8 * sg;

  floatx4 acc[4][4];
  #pragma unroll
  for (int i = 0; i < 4; i++)
    #pragma unroll
    for (int j = 0; j < 4; j++)
      acc[i][j] = floatx4{0.f, 0.f, 0.f, 0.f};

  for (int k0 = 0; k0 < K; k0 += 64) {
    __syncthreads();
    #pragma unroll
    for (int p = 0; p < 4; p++) {
      async_load16(aptr + (size_t)8 * p * K + k0, &As[32 * w + 8 * p][0]);
      async_load16(bptr + (size_t)8 * p * K + k0, &Bs[32 * w + 8 * p][0]);
    }
    __syncthreads();  // drains vmcnt(0): staged data visible
    #pragma unroll
    for (int kc = 0; kc < 2; kc++) {
      const int sw = 8 * ((kc * 4 + lq) ^ (lr & 7));
      bf16x8 af[4], bfv[4];
      #pragma unroll
      for (int t = 0; t < 4; t++)
        af[t] = *reinterpret_cast<const bf16x8*>(&As[wm + 16 * t + lr][sw]);
      #pragma unroll
      for (int t = 0; t < 4; t++)
        bfv[t] = *reinterpret_cast<const bf16x8*>(&Bs[wn + 16 * t + lr][sw]);
      #pragma unroll
      for (int i = 0; i < 4; i++)
        #pragma unroll
        for (int j = 0; j < 4; j++)
          acc[i][j] = __builtin_amdgcn_mfma_f32_16x16x32_bf16(af[i], bfv[j], acc[i][j], 0, 0, 0);
    }
  }

  // epilogue (C/D: col=lane&15, row=(lane>>4)*4+reg)
  #pragma unroll
  for (int i = 0; i < 4; i++) {
    int row_base = m0 + wm + 16 * i + lq * 4;
    #pragma unroll
    for (int j = 0; j < 4; j++) {
      int col = n0 + wn + 16 * j + lr;
      float bv = bias[col];
      if (MODE == 2 && col >= 1024) {
        int b = row_base >> 11, s0 = row_base & 2047;
        int c = col - 1024, h = c >> 6, d = c & 63;
        bf16* Vt = (bf16*)out + (size_t)B_ * H_ * S_ * HD_;
        bf16x4 pk;
        #pragma unroll
        for (int r = 0; r < 4; r++) pk[r] = (bf16)(acc[i][j][r] + bv);
        *reinterpret_cast<bf16x4*>(
            &Vt[(((size_t)b * H_ + h) * HD_ + d) * S_ + s0]) = pk;
        continue;
      }
      #pragma unroll
      for (int r = 0; r < 4; r++) {
        int row = row_base + r;
        float v = acc[i][j][r] + bv;
        if (MODE == 0) {
          ((float*)out)[(size_t)row * N + col] = v;
        } else if (MODE == 1) {
          int b = row >> 11, s = row & 2047;
          int h = col >> 6, d = col & 63;
          ((bf16*)out)[(((size_t)b * H_ + h) * S_ + s) * HD_ + d] =
              (bf16)(v * QSCALE);
        } else {
          int b = row >> 11, s = row & 2047;
          int h = col >> 6, d = col & 63;
          ((bf16*)out)[(((size_t)b * H_ + h) * S_ + s) * HD_ + d] = (bf16)v;
        }
      }
    }
  }
}

// ---------------------------------------------------------------------------
// Attention: 128 q-rows/block (4 waves, wave w owns 32 q as 2 groups of 16).
// Grid 1024 blocks x 4 waves = 4096 waves -> 4 waves/SIMD co-resident
// (was 2: 512-block grid AND 64KB LDS both capped occupancy at 2/SIMD).
// K/V double-buffered in LDS (32 KB total -> 4 blocks/CU), prefetch issued
// BEFORE compute, one barrier per 64-key tile. Q fragments in registers.
// S^T = K@Q^T; p = exp2(s) (scale folded into Q; no running max needed).
// P never touches LDS: the QK^T output fragment (lane holds
// P[key=16t+4lq+r][q=lr]) is remapped to the PV B-operand fragment
// (lane needs P[key=32kc+8lq+j][q=lr]) purely across the lq lane-groups:
//   U(d) dwords come from source lane 32*(lq&1)+lr, W(d) from +16,
//   register tt = lq>>1 (even/odd 16-key block). 4 ds_bpermute + 2 cndmask
//   per (g,d). Removes 24 LDS ops/iter/wave, the wave_barrier, and the
//   P-path bank conflicts.
// O^T = V^T@P^T with V^T precomputed by the KV GEMM.
// ---------------------------------------------------------------------------
__global__ __launch_bounds__(256, 4) void attn_kernel(
    const bf16* __restrict__ Q, const bf16* __restrict__ Kb,
    const bf16* __restrict__ Vt, bf16* __restrict__ out) {
  __shared__ bf16 smem[16384];  // [2][ks 4096 | vts 4096] = 32 KB

  const int tid  = threadIdx.x;
  const int w    = tid >> 6;
  const int lane = tid & 63;
  const int lr   = lane & 15;
  const int lq   = lane >> 4;
  const int q0   = blockIdx.x * 128;
  const int bh   = blockIdx.y;
  const size_t base = (size_t)bh * S_ * HD_;

  const int srow = lane >> 3;
  const int sg   = (lane & 7) ^ srow;

  // K/V staging: wave w covers tile rows [16w, 16w+16), 2 DMA instrs each
  const bf16* kptr = Kb + base + (size_t)(16 * w + srow) * HD_ + 8 * sg;
  const bf16* vptr = Vt + base + (size_t)(16 * w + srow) * S_  + 8 * sg;

  // stage tile 0 into buf 0
  #pragma unroll
  for (int p = 0; p < 2; p++) {
    async_load16(kptr + (size_t)8 * p * HD_, smem + (16 * w + 8 * p) * 64);
    async_load16(vptr + (size_t)8 * p * S_,  smem + 4096 + (16 * w + 8 * p) * 64);
  }

  // Q fragments from global (B-layout: n=lr -> q row, k=32kc+8lq+j)
  bf16x8 bq[2][2];
  #pragma unroll
  for (int g = 0; g < 2; g++) {
    const bf16* qrow = Q + base + (size_t)(q0 + 32 * w + 16 * g + lr) * HD_;
    bq[g][0] = *reinterpret_cast<const bf16x8*>(qrow + lq * 8);
    bq[g][1] = *reinterpret_cast<const bf16x8*>(qrow + 32 + lq * 8);
  }

  const int sw0 = 8 * ((0 + lq) ^ (lr & 7));
  const int sw1 = 8 * ((4 + lq) ^ (lr & 7));
  // bpermute byte indices for the P lane-group remap
  const int idxU = ((lq & 1) * 32 + lr) * 4;
  const int idxW = idxU + 64;

  float l_i[2] = {0.f, 0.f};
  floatx4 o_acc[2][4];
  #pragma unroll
  for (int g = 0; g < 2; g++)
    #pragma unroll
    for (int t = 0; t < 4; t++) o_acc[g][t] = floatx4{0.f, 0.f, 0.f, 0.f};

  __syncthreads();  // drain: tile 0 staged

  const int NIT = S_ / 64;
  for (int it = 0; it < NIT; it++) {
    bf16* ks  = smem + (it & 1) * 8192;
    bf16* vts = ks + 4096;

    // prefetch tile it+1 into the other buffer (drained at loop-end barrier)
    if (it + 1 < NIT) {
      bf16* ksn = smem + ((it + 1) & 1) * 8192;
      const int l0n = (it + 1) * 64;
      #pragma unroll
      for (int p = 0; p < 2; p++) {
        async_load16(kptr + (size_t)(l0n + 8 * p) * HD_, ksn + (16 * w + 8 * p) * 64);
        async_load16(vptr + (size_t)8 * p * S_ + l0n,    ksn + 4096 + (16 * w + 8 * p) * 64);
      }
    }

    // two half-tiles of 32 keys each: th == kc of the PV MFMA
    #pragma unroll
    for (int th = 0; th < 2; th++) {
      // QK^T + exp for t = 2*th + {0,1}; pack P to bf16 dwords in-register
      unsigned cg[2][2][2];  // [g][tt][d], all indices compile-time
      #pragma unroll
      for (int tt = 0; tt < 2; tt++) {
        const int t = 2 * th + tt;
        bf16x8 ak0 = *reinterpret_cast<const bf16x8*>(ks + (16 * t + lr) * 64 + sw0);
        bf16x8 ak1 = *reinterpret_cast<const bf16x8*>(ks + (16 * t + lr) * 64 + sw1);
        #pragma unroll
        for (int g = 0; g < 2; g++) {
          floatx4 sc = __builtin_amdgcn_mfma_f32_16x16x32_bf16(
              ak0, bq[g][0], floatx4{0.f, 0.f, 0.f, 0.f}, 0, 0, 0);
          sc = __builtin_amdgcn_mfma_f32_16x16x32_bf16(ak1, bq[g][1], sc, 0, 0, 0);
          float p0 = __builtin_amdgcn_exp2f(sc[0]);
          float p1 = __builtin_amdgcn_exp2f(sc[1]);
          float p2 = __builtin_amdgcn_exp2f(sc[2]);
          float p3 = __builtin_amdgcn_exp2f(sc[3]);
          l_i[g] += (p0 + p1) + (p2 + p3);
          cg[g][tt][0] = packbf2(p0, p1);
          cg[g][tt][1] = packbf2(p2, p3);
        }
      }

      // in-register P remap -> PV B-operand fragments
      bf16x8 bp[2];
      #pragma unroll
      for (int g = 0; g < 2; g++) {
        union { unsigned u[4]; bf16x8 v; } f;
        #pragma unroll
        for (int d = 0; d < 2; d++) {
          int X = (int)cg[g][0][d], Y = (int)cg[g][1][d];
          unsigned Ux = (unsigned)__builtin_amdgcn_ds_bpermute(idxU, X);
          unsigned Uy = (unsigned)__builtin_amdgcn_ds_bpermute(idxU, Y);
          unsigned Wx = (unsigned)__builtin_amdgcn_ds_bpermute(idxW, X);
          unsigned Wy = (unsigned)__builtin_amdgcn_ds_bpermute(idxW, Y);
          f.u[d]     = (lq < 2) ? Ux : Uy;
          f.u[2 + d] = (lq < 2) ? Wx : Wy;
        }
        bp[g] = f.v;
      }

      // O^T += V^T @ P^T for this 32-key half; V fragments shared by both g
      const int sw = th ? sw1 : sw0;
      #pragma unroll
      for (int t2 = 0; t2 < 4; t2++) {
        bf16x8 av = *reinterpret_cast<const bf16x8*>(vts + (16 * t2 + lr) * 64 + sw);
        #pragma unroll
        for (int g = 0; g < 2; g++)
          o_acc[g][t2] = __builtin_amdgcn_mfma_f32_16x16x32_bf16(av, bp[g], o_acc[g][t2], 0, 0, 0);
      }
    }

    __syncthreads();  // frees cur buf; drains prefetch -> tile it+1 ready
  }

  // finish denom: sum across the 4 lq groups sharing q=lr
  #pragma unroll
  for (int g = 0; g < 2; g++) {
    l_i[g] += __shfl_xor(l_i[g], 16, 64);
    l_i[g] += __shfl_xor(l_i[g], 32, 64);
  }

  // epilogue: out[b, s=q0+32w+16g+lr, h*64 + 16t + 4lq + r]
  const int b = bh >> 4, h = bh & 15;
  #pragma unroll
  for (int g = 0; g < 2; g++) {
    const float inv = 1.0f / l_i[g];
    const int qrow = q0 + 32 * w + 16 * g + lr;
    bf16* orow = out + ((size_t)b * S_ + qrow) * D_ + h * HD_;
    #pragma unroll
    for (int t = 0; t < 4; t++) {
      bf16x4 pk;
      #pragma unroll
      for (int r = 0; r < 4; r++) pk[r] = (bf16)(o_acc[g][t][r] * inv);
      *reinterpret_cast<bf16x4*>(&orow[16 * t + lq * 4]) = pk;
    }
  }
}

// ---------------------------------------------------------------------------
extern "C" void kernel_launch(void* const* d_in, const int* in_sizes, int n_in,
                              void* d_out, int out_size, void* d_ws, size_t ws_size,
                              hipStream_t stream) {
  const float* X_Q   = (const float*)d_in[0];
  const float* X_KV  = (const float*)d_in[1];
  const float* q_w   = (const float*)d_in[2];
  const float* q_b   = (const float*)d_in[3];
  const float* kv_w  = (const float*)d_in[4];
  const float* kv_b  = (const float*)d_in[5];
  const float* out_w = (const float*)d_in[6];
  const float* out_b = (const float*)d_in[7];
  float* out = (float*)d_out;

  char* ws = (char*)d_ws;
  const size_t MB = 1024 * 1024;
  bf16* Xq   = (bf16*)(ws + 0);         // 16MB (reused as attn output later)
  bf16* Xkv  = (bf16*)(ws + 16 * MB);   // 16MB
  bf16* Qb   = (bf16*)(ws + 32 * MB);   // 16MB  [B,H,S,HD] (pre-scaled)
  bf16* Kb   = (bf16*)(ws + 48 * MB);   // 16MB  [B,H,S,HD]; Vt follows at +16MB
  bf16* qwT  = (bf16*)(ws + 80 * MB);   // 2MB   [N=1024][K=1024]
  bf16* kvwT = (bf16*)(ws + 82 * MB);   // 4MB   [N=2048][K=1024]
  bf16* owT  = (bf16*)(ws + 86 * MB);   // 2MB
  bf16* Vt   = Kb + (size_t)B_ * H_ * S_ * HD_;  // [B,H,HD,S]
  bf16* attn = Xq;                       // alias: X_Q bf16 dead after GEMM1

  cast_both<<<16384, 256, 0, stream>>>(X_Q, Xq, X_KV, Xkv);
  transcast_all<<<4096, 256, 0, stream>>>(q_w, qwT, kv_w, kvwT, out_w, owT);

  // Q = (Xq @ q_w + q_b) * QSCALE -> head-split layout
  gemm_bt<1><<<dim3(8, 64), 256, 0, stream>>>(Xq, qwT, q_b, Qb, 8192, 1024, 1024);
  // KV = Xkv @ kv_w + kv_b -> K head-split, V transposed
  gemm_bt<2><<<dim3(16, 64), 256, 0, stream>>>(Xkv, kvwT, kv_b, Kb, 8192, 2048, 1024);
  // attention (128 q-rows per block, 1024 blocks = 4 blocks/CU exactly)
  attn_kernel<<<dim3(16, 64), 256, 0, stream>>>(Qb, Kb, Vt, attn);
  // out = attn @ out_w + out_b  (fp32)
  gemm_bt<0><<<dim3(8, 64), 256, 0, stream>>>(attn, owT, out_b, out, 8192, 1024, 1024);
}

// Round 3
// 308.467 us; speedup vs baseline: 1.1343x; 1.1343x over previous
//
#include <hip/hip_runtime.h>
#include <hip/hip_bf16.h>
#include <math.h>

// Problem constants
#define B_  4
#define S_  2048
#define D_  1024
#define H_  16
#define HD_ 64

typedef __bf16 bf16;
typedef __bf16 bf16x4 __attribute__((ext_vector_type(4)));
typedef __bf16 bf16x8 __attribute__((ext_vector_type(8)));
typedef float  floatx4 __attribute__((ext_vector_type(4)));
typedef unsigned short ushort8 __attribute__((ext_vector_type(8)));

// log2(e)/8: folds the 1/sqrt(64) attention scale AND the exp->exp2 change
// of base into the Q projection epilogue.
#define QSCALE 0.18033688011112042f

// Async global->LDS DMA, 16B/lane. LDS dest = wave-uniform base + lane*16.
__device__ __forceinline__ void async_load16(const bf16* g, bf16* l) {
  __builtin_amdgcn_global_load_lds(
      (const __attribute__((address_space(1))) void*)g,
      (__attribute__((address_space(3))) void*)l, 16, 0, 0);
}

// ---------------------------------------------------------------------------
// fp32 -> bf16 cast for BOTH X inputs in one launch (8192 blocks each)
// ---------------------------------------------------------------------------
__global__ __launch_bounds__(256) void cast_both(
    const float* __restrict__ ina, bf16* __restrict__ outa,
    const float* __restrict__ inb, bf16* __restrict__ outb) {
  int bid = blockIdx.x;
  const float* in;
  bf16* out;
  int i;
  if (bid < 8192) { in = ina; out = outa; i = (bid * 256 + threadIdx.x) * 4; }
  else            { in = inb; out = outb; i = ((bid - 8192) * 256 + threadIdx.x) * 4; }
  float4 v = *reinterpret_cast<const float4*>(in + i);
  bf16x4 o;
  o[0] = (bf16)v.x; o[1] = (bf16)v.y; o[2] = (bf16)v.z; o[3] = (bf16)v.w;
  *reinterpret_cast<bf16x4*>(out + i) = o;
}

// ---------------------------------------------------------------------------
// fp32 [K][N] -> bf16 [N][K] transpose+cast for all 3 weights in one launch.
// K=1024 for all; N=1024 (q_w), 2048 (kv_w), 1024 (out_w).
// ---------------------------------------------------------------------------
__global__ __launch_bounds__(256) void transcast_all(
    const float* __restrict__ qw, bf16* __restrict__ qwT,
    const float* __restrict__ kvw, bf16* __restrict__ kvwT,
    const float* __restrict__ ow, bf16* __restrict__ owT) {
  __shared__ float tile[32][33];
  int bid = blockIdx.x;
  const float* in; bf16* out; int N, lb;
  if (bid < 1024)      { in = qw;  out = qwT;  N = 1024; lb = bid; }
  else if (bid < 3072) { in = kvw; out = kvwT; N = 2048; lb = bid - 1024; }
  else                 { in = ow;  out = owT;  N = 1024; lb = bid - 3072; }
  int nx = N >> 5;
  int n0 = (lb % nx) * 32, k0 = (lb / nx) * 32;
  int tx = threadIdx.x & 31, ty = threadIdx.x >> 5;  // 32 x 8
  #pragma unroll
  for (int i = ty; i < 32; i += 8)
    tile[i][tx] = in[(size_t)(k0 + i) * N + n0 + tx];
  __syncthreads();
  #pragma unroll
  for (int i = ty; i < 32; i += 8)
    out[(size_t)(n0 + i) * 1024 + k0 + tx] = (bf16)tile[tx][i];
}

// ---------------------------------------------------------------------------
// bf16 GEMM, m97 structure: C[M,N] = A[M,K] @ Bt[N,K]^T + bias[N]
// 128x128 tile, BK=64, global_load_lds(16B) staging, XOR-swizzled LDS.
// MODE 0: fp32 out row-major [M,N]
// MODE 1: bf16 out in Q layout [B,H,S,HD], scaled by QSCALE (N==1024)
// MODE 2: bf16 out; K half -> [B,H,S,HD]; V half -> TRANSPOSED [B,H,HD,S]
// ---------------------------------------------------------------------------
template <int MODE>
__global__ __launch_bounds__(256) void gemm_bt(
    const bf16* __restrict__ A, const bf16* __restrict__ Bt,
    const float* __restrict__ bias, void* __restrict__ out,
    int M, int N, int K) {
  __shared__ bf16 As[128][64];
  __shared__ bf16 Bs[128][64];

  const int tid  = threadIdx.x;
  const int m0   = blockIdx.y * 128;
  const int n0   = blockIdx.x * 128;
  const int w    = tid >> 6;
  const int lane = tid & 63;
  const int lr   = lane & 15;
  const int lq   = lane >> 4;
  const int wm   = (w >> 1) * 64;
  const int wn   = (w & 1) * 64;

  const int srow = lane >> 3;
  const int sg   = (lane & 7) ^ srow;
  const bf16* aptr = A  + (size_t)(m0 + 32 * w + srow) * K + 8 * sg;
  const bf16* bptr = Bt + (size_t)(n0 + 32 * w + srow) * K + 8 * sg;

  floatx4 acc[4][4];
  #pragma unroll
  for (int i = 0; i < 4; i++)
    #pragma unroll
    for (int j = 0; j < 4; j++)
      acc[i][j] = floatx4{0.f, 0.f, 0.f, 0.f};

  for (int k0 = 0; k0 < K; k0 += 64) {
    __syncthreads();
    #pragma unroll
    for (int p = 0; p < 4; p++) {
      async_load16(aptr + (size_t)8 * p * K + k0, &As[32 * w + 8 * p][0]);
      async_load16(bptr + (size_t)8 * p * K + k0, &Bs[32 * w + 8 * p][0]);
    }
    __syncthreads();  // drains vmcnt(0): staged data visible
    #pragma unroll
    for (int kc = 0; kc < 2; kc++) {
      const int sw = 8 * ((kc * 4 + lq) ^ (lr & 7));
      bf16x8 af[4], bfv[4];
      #pragma unroll
      for (int t = 0; t < 4; t++)
        af[t] = *reinterpret_cast<const bf16x8*>(&As[wm + 16 * t + lr][sw]);
      #pragma unroll
      for (int t = 0; t < 4; t++)
        bfv[t] = *reinterpret_cast<const bf16x8*>(&Bs[wn + 16 * t + lr][sw]);
      #pragma unroll
      for (int i = 0; i < 4; i++)
        #pragma unroll
        for (int j = 0; j < 4; j++)
          acc[i][j] = __builtin_amdgcn_mfma_f32_16x16x32_bf16(af[i], bfv[j], acc[i][j], 0, 0, 0);
    }
  }

  // epilogue (C/D: col=lane&15, row=(lane>>4)*4+reg)
  #pragma unroll
  for (int i = 0; i < 4; i++) {
    int row_base = m0 + wm + 16 * i + lq * 4;
    #pragma unroll
    for (int j = 0; j < 4; j++) {
      int col = n0 + wn + 16 * j + lr;
      float bv = bias[col];
      if (MODE == 2 && col >= 1024) {
        int b = row_base >> 11, s0 = row_base & 2047;
        int c = col - 1024, h = c >> 6, d = c & 63;
        bf16* Vt = (bf16*)out + (size_t)B_ * H_ * S_ * HD_;
        bf16x4 pk;
        #pragma unroll
        for (int r = 0; r < 4; r++) pk[r] = (bf16)(acc[i][j][r] + bv);
        *reinterpret_cast<bf16x4*>(
            &Vt[(((size_t)b * H_ + h) * HD_ + d) * S_ + s0]) = pk;
        continue;
      }
      #pragma unroll
      for (int r = 0; r < 4; r++) {
        int row = row_base + r;
        float v = acc[i][j][r] + bv;
        if (MODE == 0) {
          ((float*)out)[(size_t)row * N + col] = v;
        } else if (MODE == 1) {
          int b = row >> 11, s = row & 2047;
          int h = col >> 6, d = col & 63;
          ((bf16*)out)[(((size_t)b * H_ + h) * S_ + s) * HD_ + d] =
              (bf16)(v * QSCALE);
        } else {
          int b = row >> 11, s = row & 2047;
          int h = col >> 6, d = col & 63;
          ((bf16*)out)[(((size_t)b * H_ + h) * S_ + s) * HD_ + d] = (bf16)v;
        }
      }
    }
  }
}

// ---------------------------------------------------------------------------
// Attention: 256 q-rows/block (4 waves, wave w owns 64 q as 4 groups of 16).
// Round-0 structure (g=4, P via per-wave LDS) + 3-PHASE iteration:
//   A: QK^T t=0,1 (P key-chunks 0-3)
//   B: PV kc=0 (reads chunks 0-3)  OVERLAPPED with  QK^T t=2,3 (writes 4-7)
//   C: PV kc=1 (reads chunks 4-7)
// Chunk sets {0-3} and {4-7} map under the XOR-(q&7) swizzle to complementary
// physical slot halves (bit-2 split preserved), so phase B's reads and writes
// are address-disjoint: no barrier between them, only wave_barriers A->B and
// B->C. This lets exp2/pack VALU of half the QK^T run under PV's MFMAs
// (separate pipes) instead of the fully-serial 2-phase round-0 schedule.
// Grid swapped to bh-major: the 8 q-tiles of a head share an XCD
// (linear id % 8 == bh % 8), so each XCD's resident K/V set = 8 heads
// x 512KB = 4MB = L2 size.
// S^T = K@Q^T; p = exp2(s) (scale folded into Q; no running max needed).
// O^T = V^T@P^T with V^T precomputed by the KV GEMM.
// LDS: ks/vts x2 = 32 KB + P 32 KB = 64 KB -> 2 blocks/CU.
// ---------------------------------------------------------------------------
__global__ __launch_bounds__(256, 2) void attn_kernel(
    const bf16* __restrict__ Q, const bf16* __restrict__ Kb,
    const bf16* __restrict__ Vt, bf16* __restrict__ out) {
  __shared__ bf16 smem[32768];  // [2][ks 4096 | vts 4096] | pw 4x4096

  const int tid  = threadIdx.x;
  const int w    = tid >> 6;
  const int lane = tid & 63;
  const int lr   = lane & 15;
  const int lq   = lane >> 4;
  const int bh   = blockIdx.x;          // x-major -> head's q-tiles same XCD
  const int q0   = blockIdx.y * 256;
  const size_t base = (size_t)bh * S_ * HD_;

  bf16* pw = smem + 16384 + w * 4096;  // wave's P: [64 q][64 keys], swizzled

  const int srow = lane >> 3;
  const int sg   = (lane & 7) ^ srow;

  // K/V staging: wave w covers tile rows [16w, 16w+16), 2 DMA instrs each
  const bf16* kptr = Kb + base + (size_t)(16 * w + srow) * HD_ + 8 * sg;
  const bf16* vptr = Vt + base + (size_t)(16 * w + srow) * S_  + 8 * sg;

  // stage tile 0 into buf 0
  #pragma unroll
  for (int p = 0; p < 2; p++) {
    async_load16(kptr + (size_t)8 * p * HD_, smem + (16 * w + 8 * p) * 64);
    async_load16(vptr + (size_t)8 * p * S_,  smem + 4096 + (16 * w + 8 * p) * 64);
  }

  // Q fragments from global (B-layout: n=lr -> q row, k=32kc+8lq+j)
  bf16x8 bq[4][2];
  #pragma unroll
  for (int g = 0; g < 4; g++) {
    const bf16* qrow = Q + base + (size_t)(q0 + 64 * w + 16 * g + lr) * HD_;
    bq[g][0] = *reinterpret_cast<const bf16x8*>(qrow + lq * 8);
    bq[g][1] = *reinterpret_cast<const bf16x8*>(qrow + 32 + lq * 8);
  }

  const int sw0 = 8 * ((0 + lq) ^ (lr & 7));
  const int sw1 = 8 * ((4 + lq) ^ (lr & 7));
  const int pcolbase = 4 * (lq & 1);
  const int pswz = lr & 7;

  float l_i[4] = {0.f, 0.f, 0.f, 0.f};
  floatx4 o_acc[4][4];
  #pragma unroll
  for (int g = 0; g < 4; g++)
    #pragma unroll
    for (int t = 0; t < 4; t++) o_acc[g][t] = floatx4{0.f, 0.f, 0.f, 0.f};

  __syncthreads();  // drain: tile 0 staged (bq loads waited via vmcnt too)

  const int NIT = S_ / 64;
  for (int it = 0; it < NIT; it++) {
    bf16* ks  = smem + (it & 1) * 8192;
    bf16* vts = ks + 4096;

    // prefetch tile it+1 into the other buffer (drained at loop-end barrier)
    if (it + 1 < NIT) {
      bf16* ksn = smem + ((it + 1) & 1) * 8192;
      const int l0n = (it + 1) * 64;
      #pragma unroll
      for (int p = 0; p < 2; p++) {
        async_load16(kptr + (size_t)(l0n + 8 * p) * HD_, ksn + (16 * w + 8 * p) * 64);
        async_load16(vptr + (size_t)8 * p * S_ + l0n,    ksn + 4096 + (16 * w + 8 * p) * 64);
      }
    }

    // QK^T + exp + P-write for one 16-key block t (keys 16t..16t+15)
    auto qkt = [&](int t) {
      bf16x8 ak0 = *reinterpret_cast<const bf16x8*>(ks + (16 * t + lr) * 64 + sw0);
      bf16x8 ak1 = *reinterpret_cast<const bf16x8*>(ks + (16 * t + lr) * 64 + sw1);
      floatx4 sc[4];
      #pragma unroll
      for (int g = 0; g < 4; g++) {
        sc[g] = __builtin_amdgcn_mfma_f32_16x16x32_bf16(ak0, bq[g][0],
                    floatx4{0.f, 0.f, 0.f, 0.f}, 0, 0, 0);
        sc[g] = __builtin_amdgcn_mfma_f32_16x16x32_bf16(ak1, bq[g][1], sc[g], 0, 0, 0);
      }
      const int pcol = 8 * ((2 * t + (lq >> 1)) ^ pswz) + pcolbase;
      #pragma unroll
      for (int g = 0; g < 4; g++) {
        bf16x4 pk;
        float lsum = 0.f;
        #pragma unroll
        for (int r = 0; r < 4; r++) {
          float p = __builtin_amdgcn_exp2f(sc[g][r]);
          lsum += p;
          pk[r] = (bf16)p;
        }
        l_i[g] += lsum;
        *reinterpret_cast<bf16x4*>(&pw[(16 * g + lr) * 64 + pcol]) = pk;
      }
    };

    // ---- phase A: QK^T for keys 0-31 (P chunks 0-3) ----
    qkt(0);
    qkt(1);
    __builtin_amdgcn_wave_barrier();  // pin same-wave ds_write -> ds_read

    // ---- phase B: PV kc=0 (chunks 0-3) overlapped with QK^T t=2,3 ----
    {
      bf16x8 bp0[4], av0[4];
      #pragma unroll
      for (int g = 0; g < 4; g++)
        bp0[g] = *reinterpret_cast<const bf16x8*>(&pw[(16 * g + lr) * 64 + sw0]);
      #pragma unroll
      for (int t2 = 0; t2 < 4; t2++)
        av0[t2] = *reinterpret_cast<const bf16x8*>(vts + (16 * t2 + lr) * 64 + sw0);
      qkt(2);
      #pragma unroll
      for (int t2 = 0; t2 < 2; t2++)
        #pragma unroll
        for (int g = 0; g < 4; g++)
          o_acc[g][t2] = __builtin_amdgcn_mfma_f32_16x16x32_bf16(av0[t2], bp0[g], o_acc[g][t2], 0, 0, 0);
      qkt(3);
      #pragma unroll
      for (int t2 = 2; t2 < 4; t2++)
        #pragma unroll
        for (int g = 0; g < 4; g++)
          o_acc[g][t2] = __builtin_amdgcn_mfma_f32_16x16x32_bf16(av0[t2], bp0[g], o_acc[g][t2], 0, 0, 0);
    }
    __builtin_amdgcn_wave_barrier();  // pin t=2,3 P-writes -> kc=1 reads

    // ---- phase C: PV kc=1 (chunks 4-7) ----
    {
      bf16x8 bp1[4];
      #pragma unroll
      for (int g = 0; g < 4; g++)
        bp1[g] = *reinterpret_cast<const bf16x8*>(&pw[(16 * g + lr) * 64 + sw1]);
      #pragma unroll
      for (int t2 = 0; t2 < 4; t2++) {
        bf16x8 av = *reinterpret_cast<const bf16x8*>(vts + (16 * t2 + lr) * 64 + sw1);
        #pragma unroll
        for (int g = 0; g < 4; g++)
          o_acc[g][t2] = __builtin_amdgcn_mfma_f32_16x16x32_bf16(av, bp1[g], o_acc[g][t2], 0, 0, 0);
      }
    }

    __syncthreads();  // frees cur buf; drains prefetch -> tile it+1 ready
  }

  // finish denom: sum across the 4 lq groups sharing q=lr
  #pragma unroll
  for (int g = 0; g < 4; g++) {
    l_i[g] += __shfl_xor(l_i[g], 16, 64);
    l_i[g] += __shfl_xor(l_i[g], 32, 64);
  }

  // epilogue: out[b, s=q0+64w+16g+lr, h*64 + 16t + 4lq + r]
  const int b = bh >> 4, h = bh & 15;
  #pragma unroll
  for (int g = 0; g < 4; g++) {
    const float inv = 1.0f / l_i[g];
    const int qrow = q0 + 64 * w + 16 * g + lr;
    bf16* orow = out + ((size_t)b * S_ + qrow) * D_ + h * HD_;
    #pragma unroll
    for (int t = 0; t < 4; t++) {
      bf16x4 pk;
      #pragma unroll
      for (int r = 0; r < 4; r++) pk[r] = (bf16)(o_acc[g][t][r] * inv);
      *reinterpret_cast<bf16x4*>(&orow[16 * t + lq * 4]) = pk;
    }
  }
}

// ---------------------------------------------------------------------------
extern "C" void kernel_launch(void* const* d_in, const int* in_sizes, int n_in,
                              void* d_out, int out_size, void* d_ws, size_t ws_size,
                              hipStream_t stream) {
  const float* X_Q   = (const float*)d_in[0];
  const float* X_KV  = (const float*)d_in[1];
  const float* q_w   = (const float*)d_in[2];
  const float* q_b   = (const float*)d_in[3];
  const float* kv_w  = (const float*)d_in[4];
  const float* kv_b  = (const float*)d_in[5];
  const float* out_w = (const float*)d_in[6];
  const float* out_b = (const float*)d_in[7];
  float* out = (float*)d_out;

  char* ws = (char*)d_ws;
  const size_t MB = 1024 * 1024;
  bf16* Xq   = (bf16*)(ws + 0);         // 16MB (reused as attn output later)
  bf16* Xkv  = (bf16*)(ws + 16 * MB);   // 16MB
  bf16* Qb   = (bf16*)(ws + 32 * MB);   // 16MB  [B,H,S,HD] (pre-scaled)
  bf16* Kb   = (bf16*)(ws + 48 * MB);   // 16MB  [B,H,S,HD]; Vt follows at +16MB
  bf16* qwT  = (bf16*)(ws + 80 * MB);   // 2MB   [N=1024][K=1024]
  bf16* kvwT = (bf16*)(ws + 82 * MB);   // 4MB   [N=2048][K=1024]
  bf16* owT  = (bf16*)(ws + 86 * MB);   // 2MB
  bf16* Vt   = Kb + (size_t)B_ * H_ * S_ * HD_;  // [B,H,HD,S]
  bf16* attn = Xq;                       // alias: X_Q bf16 dead after GEMM1

  cast_both<<<16384, 256, 0, stream>>>(X_Q, Xq, X_KV, Xkv);
  transcast_all<<<4096, 256, 0, stream>>>(q_w, qwT, kv_w, kvwT, out_w, owT);

  // Q = (Xq @ q_w + q_b) * QSCALE -> head-split layout
  gemm_bt<1><<<dim3(8, 64), 256, 0, stream>>>(Xq, qwT, q_b, Qb, 8192, 1024, 1024);
  // KV = Xkv @ kv_w + kv_b -> K head-split, V transposed
  gemm_bt<2><<<dim3(16, 64), 256, 0, stream>>>(Xkv, kvwT, kv_b, Kb, 8192, 2048, 1024);
  // attention (256 q-rows per block; bh-major grid for XCD/L2 locality)
  attn_kernel<<<dim3(64, 8), 256, 0, stream>>>(Qb, Kb, Vt, attn);
  // out = attn @ out_w + out_b  (fp32)
  gemm_bt<0><<<dim3(8, 64), 256, 0, stream>>>(attn, owT, out_b, out, 8192, 1024, 1024);
}